// Round 5
// baseline (492.987 us; speedup 1.0000x reference)
//
#include <hip/hip_runtime.h>

// MultiheadSelfAttention w/ RoPE, causal. B=2 S=2048 D=1024 NH=16 HD=64.
// cvt_all -> gemm_qkv (m97 global_load_lds staging, RoPE fused in epilogue,
// q pre-scaled by 0.125*log2e) -> attn (S^T/O^T, no-max exp2 softmax,
// K/V frags loaded straight from global, barrier-free K-loop) -> gemm_out.

typedef unsigned short u16;
typedef unsigned int   u32;
typedef unsigned long long u64;
using s16x8 = __attribute__((ext_vector_type(8))) short;  // 8 bf16
using f32x4 = __attribute__((ext_vector_type(4))) float;  // 4 fp32 acc

__device__ __forceinline__ u16 f2bf(float f) {
  union { float f; u32 u; } v; v.f = f;
  return (u16)((v.u + 0x7fffu + ((v.u >> 16) & 1u)) >> 16);  // RNE
}

// async 16B global->LDS (DMA; LDS dest = wave-uniform base + lane*16)
__device__ __forceinline__ void gl2lds(const u16* g, u16* l) {
  __builtin_amdgcn_global_load_lds(
      (const __attribute__((address_space(1))) void*)g,
      (__attribute__((address_space(3))) void*)l, 16, 0, 0);
}

// ---------------------------------------------------------------- cvt (fused)
__global__ __launch_bounds__(256) void cvt_all(
    const float* __restrict__ x,
    const float* __restrict__ wq, const float* __restrict__ wk,
    const float* __restrict__ wv, const float* __restrict__ wo,
    u16* __restrict__ xb, u16* __restrict__ wqb, u16* __restrict__ wkb,
    u16* __restrict__ wvb, u16* __restrict__ wob) {
  int e = (blockIdx.x * 256 + threadIdx.x) * 4;
  const float* src; u16* dst; int off;
  const int XN = 4 << 20;
  if (e < XN) { src = x; dst = xb; off = e; }
  else {
    int t = e - XN; int sel = t >> 20; off = t & ((1 << 20) - 1);
    src = sel == 0 ? wq : sel == 1 ? wk : sel == 2 ? wv : wo;
    dst = sel == 0 ? wqb : sel == 1 ? wkb : sel == 2 ? wvb : wob;
  }
  float4 v = *(const float4*)(src + off);
  ushort4 o;
  o.x = f2bf(v.x); o.y = f2bf(v.y); o.z = f2bf(v.z); o.w = f2bf(v.w);
  *(ushort4*)(dst + off) = o;
}

// ---------------------------------------------------------------- GEMM core
// m97 structure: C[128x128] = A[128xK] . W[128xK]^T, bf16, BK=32.
// LDS tiles [128][32] u16 UNPADDED (global_load_lds lane layout).
__device__ __forceinline__ void gemm_core(
    const u16* __restrict__ A, const u16* __restrict__ W,
    u16* As, u16* Bs, int bm0, int bn0, f32x4 (&acc)[4][4]) {
  const int K = 1024;
  int tid = threadIdx.x;
  int wid = tid >> 6, lane = tid & 63, quad = lane >> 4, l15 = lane & 15;
  int wm = (wid >> 1) * 64, wn = (wid & 1) * 64;
  int ch0 = wid * 128 + lane, ch1 = ch0 + 64;
  int r0 = ch0 >> 2, c0 = (ch0 & 3) * 8;
  int r1 = ch1 >> 2, c1 = (ch1 & 3) * 8;
  const u16* Ab = A + (size_t)bm0 * K;
  const u16* Wb = W + (size_t)bn0 * K;
  u16* lA0 = As + wid * 1024; u16* lA1 = lA0 + 512;
  u16* lB0 = Bs + wid * 1024; u16* lB1 = lB0 + 512;
  for (int k0 = 0; k0 < K; k0 += 32) {
    __syncthreads();
    gl2lds(Ab + (size_t)r0 * K + k0 + c0, lA0);
    gl2lds(Ab + (size_t)r1 * K + k0 + c1, lA1);
    gl2lds(Wb + (size_t)r0 * K + k0 + c0, lB0);
    gl2lds(Wb + (size_t)r1 * K + k0 + c1, lB1);
    __syncthreads();
    s16x8 af[4], bf[4];
#pragma unroll
    for (int mi = 0; mi < 4; mi++)
      af[mi] = *(const s16x8*)(As + (wm + mi * 16 + l15) * 32 + quad * 8);
#pragma unroll
    for (int ni = 0; ni < 4; ni++)
      bf[ni] = *(const s16x8*)(Bs + (wn + ni * 16 + l15) * 32 + quad * 8);
#pragma unroll
    for (int mi = 0; mi < 4; mi++)
#pragma unroll
      for (int ni = 0; ni < 4; ni++)
        acc[mi][ni] = __builtin_amdgcn_mfma_f32_16x16x32_bf16(
            af[mi], bf[ni], acc[mi][ni], 0, 0, 0);
  }
}

// ---------------------------------------------------------------- QKV proj
// z=0: q (RoPE + 0.125*log2e scale) -> [B][NH][S][HD]
// z=1: k (RoPE) -> same; z=2: v -> [B][NH][HD][S] transposed.
__global__ __launch_bounds__(256) void gemm_qkv(
    const u16* __restrict__ xb,
    const u16* __restrict__ wq, const u16* __restrict__ wk,
    const u16* __restrict__ wv, const int* __restrict__ pos,
    u16* __restrict__ qh, u16* __restrict__ kh, u16* __restrict__ vt) {
  __shared__ __align__(16) u16 As[128 * 32];
  __shared__ __align__(16) u16 Bs[128 * 32];
  int z = blockIdx.z;
  const u16* W = (z == 0) ? wq : (z == 1) ? wk : wv;
  int bm0 = blockIdx.y * 128, bn0 = blockIdx.x * 128;
  f32x4 acc[4][4];
  const f32x4 fz = {0.f, 0.f, 0.f, 0.f};
#pragma unroll
  for (int mi = 0; mi < 4; mi++)
#pragma unroll
    for (int ni = 0; ni < 4; ni++) acc[mi][ni] = fz;
  gemm_core(xb, W, As, Bs, bm0, bn0, acc);
  int tid = threadIdx.x, wid = tid >> 6, lane = tid & 63;
  int quad = lane >> 4, l15 = lane & 15;
  int wm = (wid >> 1) * 64, wn = (wid & 1) * 64;
  if (z < 2) {
    u16* dst = (z == 0) ? qh : kh;
    float sc = (z == 0) ? 0.18033688011112042f : 1.0f;  // 0.125*log2(e)
    float frq[4], sgn[4];
#pragma unroll
    for (int ni = 0; ni < 4; ni++) {
      int d = (bn0 + wn + ni * 16 + l15) & 63;
      frq[ni] = __expf(-0.28782313662425572f * (float)(d >> 1));
      sgn[ni] = (d & 1) ? 1.f : -1.f;
    }
#pragma unroll
    for (int mi = 0; mi < 4; mi++)
#pragma unroll
      for (int r = 0; r < 4; r++) {
        int row = bm0 + wm + mi * 16 + quad * 4 + r;
        int b = row >> 11, s = row & 2047;
        float pv = (float)pos[s];
#pragma unroll
        for (int ni = 0; ni < 4; ni++) {
          float v = acc[mi][ni][r];
          float prt = __shfl_xor(v, 1, 64);  // partner d^1 (lane^1)
          float ang = pv * frq[ni], sn, cs;
          sincosf(ang, &sn, &cs);
          float res = (v * cs + sgn[ni] * prt * sn) * sc;
          int col = bn0 + wn + ni * 16 + l15;
          int h = col >> 6, d = col & 63;
          dst[(((size_t)(b * 16 + h)) * 2048 + s) * 64 + d] = f2bf(res);
        }
      }
  } else {
#pragma unroll
    for (int mi = 0; mi < 4; mi++)
#pragma unroll
      for (int ni = 0; ni < 4; ni++) {
        int row0 = bm0 + wm + mi * 16 + quad * 4;
        int col = bn0 + wn + ni * 16 + l15;
        int b = row0 >> 11, s0 = row0 & 2047, h = col >> 6, d = col & 63;
        u64 pk = (u64)f2bf(acc[mi][ni][0]) |
                 ((u64)f2bf(acc[mi][ni][1]) << 16) |
                 ((u64)f2bf(acc[mi][ni][2]) << 32) |
                 ((u64)f2bf(acc[mi][ni][3]) << 48);
        *(u64*)(vt + (((size_t)(b * 16 + h)) * 64 + d) * 2048 + s0) = pk;
      }
  }
}

// ---------------------------------------------------------------- out proj
__global__ __launch_bounds__(256) void gemm_out(
    const u16* __restrict__ ao, const u16* __restrict__ wo,
    float* __restrict__ out) {
  __shared__ __align__(16) u16 As[128 * 32];
  __shared__ __align__(16) u16 Bs[128 * 32];
  int bm0 = blockIdx.y * 128, bn0 = blockIdx.x * 128;
  f32x4 acc[4][4];
  const f32x4 fz = {0.f, 0.f, 0.f, 0.f};
#pragma unroll
  for (int mi = 0; mi < 4; mi++)
#pragma unroll
    for (int ni = 0; ni < 4; ni++) acc[mi][ni] = fz;
  gemm_core(ao, wo, As, Bs, bm0, bn0, acc);
  int tid = threadIdx.x, wid = tid >> 6, lane = tid & 63;
  int quad = lane >> 4, l15 = lane & 15;
  int wm = (wid >> 1) * 64, wn = (wid & 1) * 64;
#pragma unroll
  for (int mi = 0; mi < 4; mi++)
#pragma unroll
    for (int ni = 0; ni < 4; ni++)
#pragma unroll
      for (int r = 0; r < 4; r++) {
        int row = bm0 + wm + mi * 16 + quad * 4 + r;
        int col = bn0 + wn + ni * 16 + l15;
        out[(size_t)row * 1024 + col] = acc[mi][ni][r];
      }
}

// ---------------------------------------------------------------- attention
// S^T = K.Q^T, O^T = V^T.P^T; p = exp2(score) (log2e folded into q scale).
// K/V MFMA frags loaded directly from global (coalesced b128, L2-resident
// via XCD swizzle); LDS only for the per-wave P C->A round trip -> NO
// barriers in the K-loop. K frags prefetched one iter ahead.
// Block: 32 q (2 qsub waves) x 64-t tiles split across 2 thalf wave-pairs.
// Grid 1024; id = bh + 32*pi; phases pair (pi, 63-pi) for uniform work.
#define PTS 40  // per-wave P^T [q=16][t=32+pad]
#define OTS 72

__global__ __launch_bounds__(256, 4) void attn_k(
    const u16* __restrict__ qh, const u16* __restrict__ kh,
    const u16* __restrict__ vt, u16* __restrict__ ao) {
  __shared__ __align__(16) u16 pt[4 * 16 * PTS];  // per-wave P^T (+ O stage)
  __shared__ float redo[128 * 17];                // thalf O-reduction scratch
  __shared__ float redl[128];
  int bid = blockIdx.x;
  int bh = bid & 31, pi = bid >> 5;
  int b = bh >> 4, h = bh & 15;
  int tid = threadIdx.x, wid = tid >> 6, lane = tid & 63;
  int quad = lane >> 4, l15 = lane & 15;
  int qsub = wid & 1, thalf = wid >> 1;
  const u16* qbase = qh + (size_t)bh * 2048 * 64;
  const u16* kbase = kh + (size_t)bh * 2048 * 64;
  const u16* vbase = vt + (size_t)bh * 64 * 2048;
  u16* ptw = pt + wid * 16 * PTS;
  const f32x4 fz = {0.f, 0.f, 0.f, 0.f};
  int tb = thalf * 32;

#pragma unroll
  for (int phase = 0; phase < 2; phase++) {
    __syncthreads();  // pt / redo safe to reuse across phases
    int qt = phase ? (63 - pi) : pi;       // q-tile of 32
    int q0 = qt * 32, q0w = q0 + qsub * 16;
    s16x8 qf0 = *(const s16x8*)(qbase + (size_t)(q0w + l15) * 64 + quad * 8);
    s16x8 qf1 = *(const s16x8*)(qbase + (size_t)(q0w + l15) * 64 + 32 + quad * 8);
    f32x4 acc[4];
#pragma unroll
    for (int md = 0; md < 4; md++) acc[md] = fz;
    float lsum = 0.f;
    int qg = q0w + l15;
    int nt = (qt >> 1) + 1;
    s16x8 ka[4];  // current K frags (A-layout, direct from global)
    {
      const u16* kr = kbase + (size_t)(tb + l15) * 64 + quad * 8;
      ka[0] = *(const s16x8*)(kr);
      ka[1] = *(const s16x8*)(kr + 32);
      ka[2] = *(const s16x8*)(kr + 1024);
      ka[3] = *(const s16x8*)(kr + 1024 + 32);
    }
    for (int it = 0; it < nt; it++) {
      int t0 = it << 6;
      s16x8 va[4];  // V frags for this iter (consumed after softmax)
#pragma unroll
      for (int md = 0; md < 4; md++)
        va[md] = *(const s16x8*)(vbase + (size_t)(md * 16 + l15) * 2048 +
                                 t0 + tb + quad * 8);
      s16x8 kn[4];  // prefetch next iter's K frags
      if (it + 1 < nt) {
        const u16* kr = kbase + (size_t)(t0 + 64 + tb + l15) * 64 + quad * 8;
        kn[0] = *(const s16x8*)(kr);
        kn[1] = *(const s16x8*)(kr + 32);
        kn[2] = *(const s16x8*)(kr + 1024);
        kn[3] = *(const s16x8*)(kr + 1024 + 32);
      }
      bool diag = (it == nt - 1);
#pragma unroll
      for (int mt = 0; mt < 2; mt++) {
        f32x4 st = __builtin_amdgcn_mfma_f32_16x16x32_bf16(ka[2 * mt], qf0, fz, 0, 0, 0);
        st = __builtin_amdgcn_mfma_f32_16x16x32_bf16(ka[2 * mt + 1], qf1, st, 0, 0, 0);
        u64 pk = 0;
#pragma unroll
        for (int r = 0; r < 4; r++) {
          float p = __builtin_amdgcn_exp2f(st[r]);
          if (diag) {
            int tg = t0 + tb + mt * 16 + quad * 4 + r;
            if (tg > qg) p = 0.f;
          }
          lsum += p;
          pk |= ((u64)f2bf(p)) << (16 * r);
        }
        *(u64*)(ptw + l15 * PTS + mt * 16 + quad * 4) = pk;
      }
      s16x8 pb = *(const s16x8*)(ptw + l15 * PTS + quad * 8);
#pragma unroll
      for (int md = 0; md < 4; md++)
        acc[md] = __builtin_amdgcn_mfma_f32_16x16x32_bf16(va[md], pb, acc[md], 0, 0, 0);
#pragma unroll
      for (int j = 0; j < 4; j++) ka[j] = kn[j];
    }
    lsum += __shfl_xor(lsum, 16, 64);
    lsum += __shfl_xor(lsum, 32, 64);
    if (thalf == 1) {
#pragma unroll
      for (int md = 0; md < 4; md++)
#pragma unroll
        for (int r = 0; r < 4; r++)
          redo[(qsub * 64 + lane) * 17 + md * 4 + r] = acc[md][r];
      redl[qsub * 64 + lane] = lsum;
    }
    __syncthreads();
    if (thalf == 0) {
#pragma unroll
      for (int md = 0; md < 4; md++)
#pragma unroll
        for (int r = 0; r < 4; r++)
          acc[md][r] += redo[(qsub * 64 + lane) * 17 + md * 4 + r];
      lsum += redl[qsub * 64 + lane];
      float rl = 1.0f / lsum;
      u16* ow = pt + qsub * 16 * OTS;
#pragma unroll
      for (int md = 0; md < 4; md++) {
        u64 ok = 0;
#pragma unroll
        for (int r = 0; r < 4; r++)
          ok |= ((u64)f2bf(acc[md][r] * rl)) << (16 * r);
        *(u64*)(ow + l15 * OTS + md * 16 + quad * 4) = ok;
      }
      int qq = lane >> 2, dc = lane & 3;
      uint4 o0 = *(uint4*)(ow + qq * OTS + dc * 16);
      uint4 o1 = *(uint4*)(ow + qq * OTS + dc * 16 + 8);
      size_t orow = (size_t)b * 2048 + q0 + qsub * 16 + qq;
      *(uint4*)(ao + orow * 1024 + h * 64 + dc * 16) = o0;
      *(uint4*)(ao + orow * 1024 + h * 64 + dc * 16 + 8) = o1;
    }
  }
}

// ---------------------------------------------------------------- launch
extern "C" void kernel_launch(void* const* d_in, const int* in_sizes, int n_in,
                              void* d_out, int out_size, void* d_ws,
                              size_t ws_size, hipStream_t stream) {
  const float* x  = (const float*)d_in[0];
  const int* pos  = (const int*)d_in[1];
  const float* Wq = (const float*)d_in[2];
  const float* Wk = (const float*)d_in[3];
  const float* Wv = (const float*)d_in[4];
  const float* Wo = (const float*)d_in[5];
  float* out = (float*)d_out;

  char* ws = (char*)d_ws;
  const size_t MB = 1u << 20;
  u16* xb  = (u16*)(ws);             // 8 MB  [4096][1024] bf16
  u16* wqb = (u16*)(ws + 8 * MB);
  u16* wkb = (u16*)(ws + 10 * MB);
  u16* wvb = (u16*)(ws + 12 * MB);
  u16* wob = (u16*)(ws + 14 * MB);
  u16* qhb = (u16*)(ws + 16 * MB);   // [B][NH][S][HD] (RoPE'd, q scaled)
  u16* khb = (u16*)(ws + 24 * MB);
  u16* vtb = (u16*)(ws + 32 * MB);   // [B][NH][HD][S]
  u16* ao  = xb;  // xb dead after gemm_qkv

  cvt_all<<<8192, 256, 0, stream>>>(x, Wq, Wk, Wv, Wo,
                                    xb, wqb, wkb, wvb, wob);
  gemm_qkv<<<dim3(8, 32, 3), 256, 0, stream>>>(xb, wqb, wkb, wvb, pos,
                                               qhb, khb, vtb);
  attn_k<<<1024, 256, 0, stream>>>(qhb, khb, vtb, ao);
  gemm_out<<<dim3(8, 32), 256, 0, stream>>>(ao, wob, out);
}

// Round 6
// 279.964 us; speedup vs baseline: 1.7609x; 1.7609x over previous
//
#include <hip/hip_runtime.h>

// MultiheadSelfAttention w/ RoPE, causal. B=2 S=2048 D=1024 NH=16 HD=64.
// cvt_all -> gemm_qkv (m97 global_load_lds staging, RoPE fused in epilogue
// via inline __sinf/__cosf — NEVER sincosf: its address-taken outputs spill
// to scratch, 1.5 GB of hidden traffic measured R5) -> attn (S^T/O^T,
// no-max exp2 softmax, K/V frags direct from global, barrier-free K-loop)
// -> gemm_out.

typedef unsigned short u16;
typedef unsigned int   u32;
typedef unsigned long long u64;
using s16x8 = __attribute__((ext_vector_type(8))) short;  // 8 bf16
using f32x4 = __attribute__((ext_vector_type(4))) float;  // 4 fp32 acc

__device__ __forceinline__ u16 f2bf(float f) {
  union { float f; u32 u; } v; v.f = f;
  return (u16)((v.u + 0x7fffu + ((v.u >> 16) & 1u)) >> 16);  // RNE
}

// async 16B global->LDS (DMA; LDS dest = wave-uniform base + lane*16)
__device__ __forceinline__ void gl2lds(const u16* g, u16* l) {
  __builtin_amdgcn_global_load_lds(
      (const __attribute__((address_space(1))) void*)g,
      (__attribute__((address_space(3))) void*)l, 16, 0, 0);
}

// ---------------------------------------------------------------- cvt (fused)
__global__ __launch_bounds__(256) void cvt_all(
    const float* __restrict__ x,
    const float* __restrict__ wq, const float* __restrict__ wk,
    const float* __restrict__ wv, const float* __restrict__ wo,
    u16* __restrict__ xb, u16* __restrict__ wqb, u16* __restrict__ wkb,
    u16* __restrict__ wvb, u16* __restrict__ wob) {
  int e = (blockIdx.x * 256 + threadIdx.x) * 4;
  const float* src; u16* dst; int off;
  const int XN = 4 << 20;
  if (e < XN) { src = x; dst = xb; off = e; }
  else {
    int t = e - XN; int sel = t >> 20; off = t & ((1 << 20) - 1);
    src = sel == 0 ? wq : sel == 1 ? wk : sel == 2 ? wv : wo;
    dst = sel == 0 ? wqb : sel == 1 ? wkb : sel == 2 ? wvb : wob;
  }
  float4 v = *(const float4*)(src + off);
  ushort4 o;
  o.x = f2bf(v.x); o.y = f2bf(v.y); o.z = f2bf(v.z); o.w = f2bf(v.w);
  *(ushort4*)(dst + off) = o;
}

// ---------------------------------------------------------------- GEMM core
// m97 structure: C[128x128] = A[128xK] . W[128xK]^T, bf16, BK=32.
// LDS tiles [128][32] u16 UNPADDED (global_load_lds lane layout).
__device__ __forceinline__ void gemm_core(
    const u16* __restrict__ A, const u16* __restrict__ W,
    u16* As, u16* Bs, int bm0, int bn0, f32x4 (&acc)[4][4]) {
  const int K = 1024;
  int tid = threadIdx.x;
  int wid = tid >> 6, lane = tid & 63, quad = lane >> 4, l15 = lane & 15;
  int wm = (wid >> 1) * 64, wn = (wid & 1) * 64;
  int ch0 = wid * 128 + lane, ch1 = ch0 + 64;
  int r0 = ch0 >> 2, c0 = (ch0 & 3) * 8;
  int r1 = ch1 >> 2, c1 = (ch1 & 3) * 8;
  const u16* Ab = A + (size_t)bm0 * K;
  const u16* Wb = W + (size_t)bn0 * K;
  u16* lA0 = As + wid * 1024; u16* lA1 = lA0 + 512;
  u16* lB0 = Bs + wid * 1024; u16* lB1 = lB0 + 512;
  for (int k0 = 0; k0 < K; k0 += 32) {
    __syncthreads();
    gl2lds(Ab + (size_t)r0 * K + k0 + c0, lA0);
    gl2lds(Ab + (size_t)r1 * K + k0 + c1, lA1);
    gl2lds(Wb + (size_t)r0 * K + k0 + c0, lB0);
    gl2lds(Wb + (size_t)r1 * K + k0 + c1, lB1);
    __syncthreads();
    s16x8 af[4], bf[4];
#pragma unroll
    for (int mi = 0; mi < 4; mi++)
      af[mi] = *(const s16x8*)(As + (wm + mi * 16 + l15) * 32 + quad * 8);
#pragma unroll
    for (int ni = 0; ni < 4; ni++)
      bf[ni] = *(const s16x8*)(Bs + (wn + ni * 16 + l15) * 32 + quad * 8);
#pragma unroll
    for (int mi = 0; mi < 4; mi++)
#pragma unroll
      for (int ni = 0; ni < 4; ni++)
        acc[mi][ni] = __builtin_amdgcn_mfma_f32_16x16x32_bf16(
            af[mi], bf[ni], acc[mi][ni], 0, 0, 0);
  }
}

// ---------------------------------------------------------------- QKV proj
// z=0: q (RoPE + 0.125*log2e scale) -> [B][NH][S][HD]
// z=1: k (RoPE) -> same; z=2: v -> [B][NH][HD][S] transposed.
__global__ __launch_bounds__(256) void gemm_qkv(
    const u16* __restrict__ xb,
    const u16* __restrict__ wq, const u16* __restrict__ wk,
    const u16* __restrict__ wv, const int* __restrict__ pos,
    u16* __restrict__ qh, u16* __restrict__ kh, u16* __restrict__ vt) {
  __shared__ __align__(16) u16 As[128 * 32];
  __shared__ __align__(16) u16 Bs[128 * 32];
  int z = blockIdx.z;
  const u16* W = (z == 0) ? wq : (z == 1) ? wk : wv;
  int bm0 = blockIdx.y * 128, bn0 = blockIdx.x * 128;
  f32x4 acc[4][4];
  const f32x4 fz = {0.f, 0.f, 0.f, 0.f};
#pragma unroll
  for (int mi = 0; mi < 4; mi++)
#pragma unroll
    for (int ni = 0; ni < 4; ni++) acc[mi][ni] = fz;
  gemm_core(xb, W, As, Bs, bm0, bn0, acc);
  int tid = threadIdx.x, wid = tid >> 6, lane = tid & 63;
  int quad = lane >> 4, l15 = lane & 15;
  int wm = (wid >> 1) * 64, wn = (wid & 1) * 64;
  if (z < 2) {
    u16* dst = (z == 0) ? qh : kh;
    float sc = (z == 0) ? 0.18033688011112042f : 1.0f;  // 0.125*log2(e)
    float frq[4], sgn[4];
#pragma unroll
    for (int ni = 0; ni < 4; ni++) {
      int d = (bn0 + wn + ni * 16 + l15) & 63;
      frq[ni] = __expf(-0.28782313662425572f * (float)(d >> 1));
      sgn[ni] = (d & 1) ? 1.f : -1.f;
    }
#pragma unroll
    for (int mi = 0; mi < 4; mi++)
#pragma unroll
      for (int r = 0; r < 4; r++) {
        int row = bm0 + wm + mi * 16 + quad * 4 + r;
        int b = row >> 11, s = row & 2047;
        float pv = (float)pos[s];
#pragma unroll
        for (int ni = 0; ni < 4; ni++) {
          float v = acc[mi][ni][r];
          float prt = __shfl_xor(v, 1, 64);  // partner d^1 (lane^1)
          float ang = pv * frq[ni];
          float sn = __sinf(ang), cs = __cosf(ang);  // inline, no scratch
          float res = (v * cs + sgn[ni] * prt * sn) * sc;
          int col = bn0 + wn + ni * 16 + l15;
          int h = col >> 6, d = col & 63;
          dst[(((size_t)(b * 16 + h)) * 2048 + s) * 64 + d] = f2bf(res);
        }
      }
  } else {
#pragma unroll
    for (int mi = 0; mi < 4; mi++)
#pragma unroll
      for (int ni = 0; ni < 4; ni++) {
        int row0 = bm0 + wm + mi * 16 + quad * 4;
        int col = bn0 + wn + ni * 16 + l15;
        int b = row0 >> 11, s0 = row0 & 2047, h = col >> 6, d = col & 63;
        u64 pk = (u64)f2bf(acc[mi][ni][0]) |
                 ((u64)f2bf(acc[mi][ni][1]) << 16) |
                 ((u64)f2bf(acc[mi][ni][2]) << 32) |
                 ((u64)f2bf(acc[mi][ni][3]) << 48);
        *(u64*)(vt + (((size_t)(b * 16 + h)) * 64 + d) * 2048 + s0) = pk;
      }
  }
}

// ---------------------------------------------------------------- out proj
__global__ __launch_bounds__(256) void gemm_out(
    const u16* __restrict__ ao, const u16* __restrict__ wo,
    float* __restrict__ out) {
  __shared__ __align__(16) u16 As[128 * 32];
  __shared__ __align__(16) u16 Bs[128 * 32];
  int bm0 = blockIdx.y * 128, bn0 = blockIdx.x * 128;
  f32x4 acc[4][4];
  const f32x4 fz = {0.f, 0.f, 0.f, 0.f};
#pragma unroll
  for (int mi = 0; mi < 4; mi++)
#pragma unroll
    for (int ni = 0; ni < 4; ni++) acc[mi][ni] = fz;
  gemm_core(ao, wo, As, Bs, bm0, bn0, acc);
  int tid = threadIdx.x, wid = tid >> 6, lane = tid & 63;
  int quad = lane >> 4, l15 = lane & 15;
  int wm = (wid >> 1) * 64, wn = (wid & 1) * 64;
#pragma unroll
  for (int mi = 0; mi < 4; mi++)
#pragma unroll
    for (int ni = 0; ni < 4; ni++)
#pragma unroll
      for (int r = 0; r < 4; r++) {
        int row = bm0 + wm + mi * 16 + quad * 4 + r;
        int col = bn0 + wn + ni * 16 + l15;
        out[(size_t)row * 1024 + col] = acc[mi][ni][r];
      }
}

// ---------------------------------------------------------------- attention
// S^T = K.Q^T, O^T = V^T.P^T; p = exp2(score) (log2e folded into q scale).
// K/V MFMA frags loaded directly from global (coalesced b128, L2-resident
// via XCD swizzle); LDS only for the per-wave P C->A round trip -> NO
// barriers in the K-loop. K frags prefetched one iter ahead.
// Block: 32 q (2 qsub waves) x 64-t tiles split across 2 thalf wave-pairs.
// Grid 1024; id = bh + 32*pi; phases pair (pi, 63-pi) for uniform work.
#define PTS 40  // per-wave P^T [q=16][t=32+pad]
#define OTS 72

__global__ __launch_bounds__(256, 4) void attn_k(
    const u16* __restrict__ qh, const u16* __restrict__ kh,
    const u16* __restrict__ vt, u16* __restrict__ ao) {
  __shared__ __align__(16) u16 pt[4 * 16 * PTS];  // per-wave P^T (+ O stage)
  __shared__ float redo[128 * 17];                // thalf O-reduction scratch
  __shared__ float redl[128];
  int bid = blockIdx.x;
  int bh = bid & 31, pi = bid >> 5;
  int b = bh >> 4, h = bh & 15;
  int tid = threadIdx.x, wid = tid >> 6, lane = tid & 63;
  int quad = lane >> 4, l15 = lane & 15;
  int qsub = wid & 1, thalf = wid >> 1;
  const u16* qbase = qh + (size_t)bh * 2048 * 64;
  const u16* kbase = kh + (size_t)bh * 2048 * 64;
  const u16* vbase = vt + (size_t)bh * 64 * 2048;
  u16* ptw = pt + wid * 16 * PTS;
  const f32x4 fz = {0.f, 0.f, 0.f, 0.f};
  int tb = thalf * 32;

#pragma unroll
  for (int phase = 0; phase < 2; phase++) {
    __syncthreads();  // pt / redo safe to reuse across phases
    int qt = phase ? (63 - pi) : pi;       // q-tile of 32
    int q0 = qt * 32, q0w = q0 + qsub * 16;
    s16x8 qf0 = *(const s16x8*)(qbase + (size_t)(q0w + l15) * 64 + quad * 8);
    s16x8 qf1 = *(const s16x8*)(qbase + (size_t)(q0w + l15) * 64 + 32 + quad * 8);
    f32x4 acc[4];
#pragma unroll
    for (int md = 0; md < 4; md++) acc[md] = fz;
    float lsum = 0.f;
    int qg = q0w + l15;
    int nt = (qt >> 1) + 1;
    s16x8 ka[4];  // current K frags (A-layout, direct from global)
    {
      const u16* kr = kbase + (size_t)(tb + l15) * 64 + quad * 8;
      ka[0] = *(const s16x8*)(kr);
      ka[1] = *(const s16x8*)(kr + 32);
      ka[2] = *(const s16x8*)(kr + 1024);
      ka[3] = *(const s16x8*)(kr + 1024 + 32);
    }
    for (int it = 0; it < nt; it++) {
      int t0 = it << 6;
      s16x8 va[4];  // V frags for this iter (consumed after softmax)
#pragma unroll
      for (int md = 0; md < 4; md++)
        va[md] = *(const s16x8*)(vbase + (size_t)(md * 16 + l15) * 2048 +
                                 t0 + tb + quad * 8);
      s16x8 kn[4];  // prefetch next iter's K frags
      if (it + 1 < nt) {
        const u16* kr = kbase + (size_t)(t0 + 64 + tb + l15) * 64 + quad * 8;
        kn[0] = *(const s16x8*)(kr);
        kn[1] = *(const s16x8*)(kr + 32);
        kn[2] = *(const s16x8*)(kr + 1024);
        kn[3] = *(const s16x8*)(kr + 1024 + 32);
      }
      bool diag = (it == nt - 1);
#pragma unroll
      for (int mt = 0; mt < 2; mt++) {
        f32x4 st = __builtin_amdgcn_mfma_f32_16x16x32_bf16(ka[2 * mt], qf0, fz, 0, 0, 0);
        st = __builtin_amdgcn_mfma_f32_16x16x32_bf16(ka[2 * mt + 1], qf1, st, 0, 0, 0);
        u64 pk = 0;
#pragma unroll
        for (int r = 0; r < 4; r++) {
          float p = __builtin_amdgcn_exp2f(st[r]);
          if (diag) {
            int tg = t0 + tb + mt * 16 + quad * 4 + r;
            if (tg > qg) p = 0.f;
          }
          lsum += p;
          pk |= ((u64)f2bf(p)) << (16 * r);
        }
        *(u64*)(ptw + l15 * PTS + mt * 16 + quad * 4) = pk;
      }
      s16x8 pb = *(const s16x8*)(ptw + l15 * PTS + quad * 8);
#pragma unroll
      for (int md = 0; md < 4; md++)
        acc[md] = __builtin_amdgcn_mfma_f32_16x16x32_bf16(va[md], pb, acc[md], 0, 0, 0);
#pragma unroll
      for (int j = 0; j < 4; j++) ka[j] = kn[j];
    }
    lsum += __shfl_xor(lsum, 16, 64);
    lsum += __shfl_xor(lsum, 32, 64);
    if (thalf == 1) {
#pragma unroll
      for (int md = 0; md < 4; md++)
#pragma unroll
        for (int r = 0; r < 4; r++)
          redo[(qsub * 64 + lane) * 17 + md * 4 + r] = acc[md][r];
      redl[qsub * 64 + lane] = lsum;
    }
    __syncthreads();
    if (thalf == 0) {
#pragma unroll
      for (int md = 0; md < 4; md++)
#pragma unroll
        for (int r = 0; r < 4; r++)
          acc[md][r] += redo[(qsub * 64 + lane) * 17 + md * 4 + r];
      lsum += redl[qsub * 64 + lane];
      float rl = 1.0f / lsum;
      u16* ow = pt + qsub * 16 * OTS;
#pragma unroll
      for (int md = 0; md < 4; md++) {
        u64 ok = 0;
#pragma unroll
        for (int r = 0; r < 4; r++)
          ok |= ((u64)f2bf(acc[md][r] * rl)) << (16 * r);
        *(u64*)(ow + l15 * OTS + md * 16 + quad * 4) = ok;
      }
      int qq = lane >> 2, dc = lane & 3;
      uint4 o0 = *(uint4*)(ow + qq * OTS + dc * 16);
      uint4 o1 = *(uint4*)(ow + qq * OTS + dc * 16 + 8);
      size_t orow = (size_t)b * 2048 + q0 + qsub * 16 + qq;
      *(uint4*)(ao + orow * 1024 + h * 64 + dc * 16) = o0;
      *(uint4*)(ao + orow * 1024 + h * 64 + dc * 16 + 8) = o1;
    }
  }
}

// ---------------------------------------------------------------- launch
extern "C" void kernel_launch(void* const* d_in, const int* in_sizes, int n_in,
                              void* d_out, int out_size, void* d_ws,
                              size_t ws_size, hipStream_t stream) {
  const float* x  = (const float*)d_in[0];
  const int* pos  = (const int*)d_in[1];
  const float* Wq = (const float*)d_in[2];
  const float* Wk = (const float*)d_in[3];
  const float* Wv = (const float*)d_in[4];
  const float* Wo = (const float*)d_in[5];
  float* out = (float*)d_out;

  char* ws = (char*)d_ws;
  const size_t MB = 1u << 20;
  u16* xb  = (u16*)(ws);             // 8 MB  [4096][1024] bf16
  u16* wqb = (u16*)(ws + 8 * MB);
  u16* wkb = (u16*)(ws + 10 * MB);
  u16* wvb = (u16*)(ws + 12 * MB);
  u16* wob = (u16*)(ws + 14 * MB);
  u16* qhb = (u16*)(ws + 16 * MB);   // [B][NH][S][HD] (RoPE'd, q scaled)
  u16* khb = (u16*)(ws + 24 * MB);
  u16* vtb = (u16*)(ws + 32 * MB);   // [B][NH][HD][S]
  u16* ao  = xb;  // xb dead after gemm_qkv

  cvt_all<<<8192, 256, 0, stream>>>(x, Wq, Wk, Wv, Wo,
                                    xb, wqb, wkb, wvb, wob);
  gemm_qkv<<<dim3(8, 32, 3), 256, 0, stream>>>(xb, wqb, wkb, wvb, pos,
                                               qhb, khb, vtb);
  attn_k<<<1024, 256, 0, stream>>>(qhb, khb, vtb, ao);
  gemm_out<<<dim3(8, 32), 256, 0, stream>>>(ao, wob, out);
}